// Round 1
// baseline (10833.541 us; speedup 1.0000x reference)
//
#include <hip/hip_runtime.h>
#include <hip/hip_bf16.h>

// ESN recurrence, B=16 T=512 F=512 H=2048 V=64.
// Integer matvecs are exact (int4 packed, v_dot8_i32_i4). FP path replicates
// XLA/Eigen f32 tanh bit patterns (chaotic quantized recurrence => ULP matters).

#define B_ 16
#define T_ 512
#define F_ 512
#define H_ 2048
#define V_ 64
#define SLICES 16
#define RPW 128      // rows per workgroup (H / SLICES)
#define NTHREADS 256
#define NWG 256      // 16 batches x 16 slices

#if defined(__has_builtin)
#if __has_builtin(__builtin_amdgcn_sdot8)
#define HAVE_SDOT8 1
#endif
#endif

__device__ __forceinline__ int sdot8(int a, int b, int c) {
#ifdef HAVE_SDOT8
  return __builtin_amdgcn_sdot8(a, b, c, false);
#else
#pragma unroll
  for (int i = 0; i < 8; ++i) {
    int av = (a << (28 - 4 * i)) >> 28;
    int bv = (b << (28 - 4 * i)) >> 28;
    c += av * bv;
  }
  return c;
#endif
}

// XLA / Eigen generic_fast_tanh_float, f32, fma form. Matches the numpy/XLA
// reference ulp-for-ulp in the mid range (the only range where h_int rounding
// is sensitive).
__device__ __forceinline__ float tanh_ref(float x) {
  float ax = fabsf(x);
  float xc = fminf(fmaxf(x, -7.90531110763549805f), 7.90531110763549805f);
  float x2 = __fmul_rn(xc, xc);
  float p = -2.76076847742355e-16f;
  p = __fmaf_rn(x2, p, 2.00018790482477e-13f);
  p = __fmaf_rn(x2, p, -8.60467152213735e-11f);
  p = __fmaf_rn(x2, p, 5.12229709037114e-08f);
  p = __fmaf_rn(x2, p, 1.48572235717979e-05f);
  p = __fmaf_rn(x2, p, 6.37261928875436e-04f);
  p = __fmaf_rn(x2, p, 4.89352455891786e-03f);
  p = __fmul_rn(xc, p);
  float q = 1.19825839466702e-06f;
  q = __fmaf_rn(x2, q, 1.18534705686654e-04f);
  q = __fmaf_rn(x2, q, 2.26843463243900e-03f);
  q = __fmaf_rn(x2, q, 4.89352518554385e-03f);
  float r = __fdiv_rn(p, q);
  return (ax < 0.0004f) ? x : r;
}

// ---- prep: pack weights to int4 nibbles ------------------------------------
__global__ void pack_weights(const int* __restrict__ Wres, const int* __restrict__ Win,
                             int* __restrict__ wr4, int* __restrict__ wi4) {
  int id = blockIdx.x * blockDim.x + threadIdx.x;
  if (id < H_ * 256) {
    const int* src = Wres + id * 8;  // row-major: id = row*256 + m
    int pk = 0;
#pragma unroll
    for (int i = 0; i < 8; ++i) pk |= (src[i] & 15) << (4 * i);
    wr4[id] = pk;
  } else {
    int id2 = id - H_ * 256;
    if (id2 < H_ * 64) {
      const int* src = Win + id2 * 8;  // id2 = row*64 + m
      int pk = 0;
#pragma unroll
      for (int i = 0; i < 8; ++i) pk |= (src[i] & 15) << (4 * i);
      wi4[id2] = pk;
    }
  }
}

// ---- prep: quantize input, split u = 8*a + m into two int4 planes ----------
__global__ void pack_u(const float* __restrict__ x, int* __restrict__ um, int* __restrict__ ua) {
  int idx = blockIdx.x * blockDim.x + threadIdx.x;
  if (idx >= B_ * T_ * 64) return;
  const float* src = x + (size_t)idx * 8;  // idx = (b*T+t)*64 + m  ->  x offset (b*T+t)*512 + m*8
  int pm = 0, pa = 0;
#pragma unroll
  for (int i = 0; i < 8; ++i) {
    int u = (int)rintf(__fmul_rn(src[i], 3.0f));  // exact: round-half-even, same as jnp.round
    int vv = u + 128;                             // nonneg; u = 8*(q-16) + (vv&7)
    pm |= (vv & 7) << (4 * i);
    pa |= (((vv >> 3) - 16) & 15) << (4 * i);
  }
  um[idx] = pm;
  ua[idx] = pa;
}

// ---- main persistent kernel ------------------------------------------------
// WG = (batch b = wg&15, slice = wg>>4). Slice owns rows [slice*128, +128).
// W_res slice in LDS (int4 packed, per-thread XOR swizzle -> conflict-free
// ds_read_b128). W_in slice + W_out slice in registers. h exchanged as packed
// int4 via global (double buffered), per-batch 16-WG atomic barrier per step.
__global__ void __launch_bounds__(NTHREADS, 1) esn_main(
    const int* __restrict__ um, const int* __restrict__ ua,
    const int* __restrict__ wr4, const int* __restrict__ wi4,
    int* __restrict__ hq, int* __restrict__ bar,
    const float* __restrict__ S_res, const float* __restrict__ S_in,
    const float* __restrict__ g_res, const float* __restrict__ g_in,
    const float* __restrict__ Wout, const float* __restrict__ Wb,
    float* __restrict__ out, int t0, int t1) {
  extern __shared__ char smem[];
  int* lds_w = (int*)smem;                              // 32768 dw (128 KiB)
  int* lds_h4 = lds_w + 32768;                          // 256 dw
  int* lds_um = lds_h4 + 256;                           // 64 dw
  int* lds_ua = lds_um + 64;                            // 64 dw
  float* lds_hf = (float*)(lds_ua + 64);                // 128 f32
  float* lds_red = lds_hf + 128;                        // 256 f32
  signed char* lds_h8 = (signed char*)(lds_red + 256);  // 128 B

  const int wg = blockIdx.x;
  const int b = wg & 15, slice = wg >> 4;
  const int tid = threadIdx.x;
  const int r = tid >> 1, half = tid & 1;
  const int grow = slice * RPW + r;
  const int swz = tid & 31;

  // load W_res slice -> LDS, swizzled per-thread private layout
  {
    const ::int4* gw = (const ::int4*)wr4;  // 64 int4 per row
    ::int4* lw = (::int4*)lds_w;
#pragma unroll
    for (int m = 0; m < 32; ++m) {
      ::int4 w = gw[grow * 64 + half * 32 + m];
      lw[tid * 32 + (m ^ swz)] = w;
    }
  }
  // W_in slice -> regs
  ::int4 rwm[8];
  {
    const ::int4* gwi = (const ::int4*)wi4;  // 16 int4 per row
#pragma unroll
    for (int m = 0; m < 8; ++m) rwm[m] = gwi[grow * 16 + half * 8 + m];
  }
  // W_out slice -> regs (thread = (v, chunk))
  const int v = tid & 63, cch = tid >> 6;
  float wo[32];
#pragma unroll
  for (int i = 0; i < 32; ++i) wo[i] = Wout[v * H_ + slice * RPW + cch * 32 + i];
  const float wbias = Wb[v];
  // row scales (even lanes only); match reference order: (S/49)*g, (S/21)*g
  float sr = 0.f, si = 0.f;
  if (half == 0) {
    sr = __fmul_rn(__fdiv_rn(S_res[grow], 49.0f), g_res[0]);
    si = __fmul_rn(__fdiv_rn(S_in[grow], 21.0f), g_in[0]);
  }

  const ::int4* lw4 = (const ::int4*)lds_w + tid * 32;
  const ::int4* lh4base = (const ::int4*)lds_h4;
  const ::int4* lum4 = (const ::int4*)lds_um + half * 8;
  const ::int4* lua4 = (const ::int4*)lds_ua + half * 8;

  for (int t = t0; t < t1; ++t) {
    const int cur = t & 1, nxt = cur ^ 1;
    // stage u nibbles + h nibbles
    if (tid < 64)
      lds_um[tid] = um[(b * T_ + t) * 64 + tid];
    else if (tid < 128)
      lds_ua[tid - 64] = ua[(b * T_ + t) * 64 + (tid - 64)];
    lds_h4[tid] = hq[(cur * 16 + b) * 256 + tid];
    __syncthreads();

    // recurrent dot: rows r, this thread does half the K range
    int acc = 0;
    const ::int4* lh = lh4base + half * 32;
#pragma unroll
    for (int m = 0; m < 32; ++m) {
      ::int4 w = lw4[m ^ swz];
      ::int4 h = lh[m];
      acc = sdot8(w.x, h.x, acc);
      acc = sdot8(w.y, h.y, acc);
      acc = sdot8(w.z, h.z, acc);
      acc = sdot8(w.w, h.w, acc);
    }
    // input dot: u = 8a + m split
    int am = 0, aa = 0;
#pragma unroll
    for (int m = 0; m < 8; ++m) {
      ::int4 w = rwm[m];
      ::int4 uM = lum4[m];
      ::int4 uA = lua4[m];
      am = sdot8(w.x, uM.x, am); am = sdot8(w.y, uM.y, am);
      am = sdot8(w.z, uM.z, am); am = sdot8(w.w, uM.w, am);
      aa = sdot8(w.x, uA.x, aa); aa = sdot8(w.y, uA.y, aa);
      aa = sdot8(w.z, uA.z, aa); aa = sdot8(w.w, uA.w, aa);
    }
    int accin = am + (aa << 3);
    acc += __shfl_xor(acc, 1);
    accin += __shfl_xor(accin, 1);

    if (half == 0) {
      int cr = min(max(acc, -32768), 32767);    // exact int16 saturation
      int ci = min(max(accin, -32768), 32767);
      float arg = __fadd_rn(__fmul_rn((float)cr, sr), __fmul_rn((float)ci, si));
      float hn = tanh_ref(arg);
      float hc = fminf(fmaxf(hn, -1.0f), 1.0f);
      int qv = (int)rintf(__fmul_rn(hc, 7.0f));
      lds_h8[r] = (signed char)qv;
      lds_hf[r] = hn;
    }
    __syncthreads();

    // pack next-h nibbles for this slice
    if (tid < 16) {
      int pk = 0;
#pragma unroll
      for (int i = 0; i < 8; ++i) pk |= (lds_h8[tid * 8 + i] & 15) << (4 * i);
      hq[(nxt * 16 + b) * 256 + slice * 16 + tid] = pk;
    }
    // fused readout partial: out[b,t,v] += sum_r h[r]*Wout[v,r]
    float racc = (slice == 0 && cch == 0) ? wbias : 0.0f;
#pragma unroll
    for (int i = 0; i < 32; ++i) racc = fmaf(lds_hf[cch * 32 + i], wo[i], racc);
    lds_red[tid] = racc;
    __syncthreads();
    if (tid < 64) {
      float s = lds_red[tid] + lds_red[tid + 64] + lds_red[tid + 128] + lds_red[tid + 192];
      atomicAdd(&out[(b * T_ + t) * V_ + tid], s);
    }

    // per-batch barrier (skip when caller runs one step per launch)
    __threadfence();
    __syncthreads();
    if (t + 1 < t1) {
      if (tid == 0) {
        __hip_atomic_fetch_add(&bar[b * 16], 1, __ATOMIC_RELEASE, __HIP_MEMORY_SCOPE_AGENT);
        const int target = SLICES * (t + 1 - t0);
        while (__hip_atomic_load(&bar[b * 16], __ATOMIC_ACQUIRE, __HIP_MEMORY_SCOPE_AGENT) < target) {
        }
      }
      __syncthreads();
    }
  }
}

extern "C" void kernel_launch(void* const* d_in, const int* in_sizes, int n_in,
                              void* d_out, int out_size, void* d_ws, size_t ws_size,
                              hipStream_t stream) {
  const float* x = (const float*)d_in[0];
  const float* S_res = (const float*)d_in[1];
  const float* S_in = (const float*)d_in[2];
  const float* g_res = (const float*)d_in[3];
  const float* g_in = (const float*)d_in[4];
  const float* Woutw = (const float*)d_in[5];
  const float* Woutb = (const float*)d_in[6];
  const int* Wres = (const int*)d_in[7];
  const int* Win = (const int*)d_in[8];

  char* ws = (char*)d_ws;
  int* bar = (int*)(ws + 0);                          // 16 counters, 64B apart
  int* hq = (int*)(ws + 1024);                        // 2*16*256 dw = 32 KiB
  int* um = (int*)(ws + 65536);                       // 2 MiB
  int* ua = (int*)(ws + 65536 + 2097152);             // 2 MiB
  int* wr4 = (int*)(ws + 65536 + 2 * 2097152);        // 2 MiB
  int* wi4 = (int*)(ws + 65536 + 3 * 2097152);        // 512 KiB

  hipMemsetAsync(d_ws, 0, 33792, stream);                       // bar + hq (h0 = 0)
  hipMemsetAsync(d_out, 0, (size_t)out_size * 4, stream);       // readout accumulates
  hipLaunchKernelGGL(pack_weights, dim3(2560), dim3(256), 0, stream, Wres, Win, wr4, wi4);
  hipLaunchKernelGGL(pack_u, dim3(2048), dim3(256), 0, stream, x, um, ua);

  const int smem_bytes = 134272;
  (void)hipFuncSetAttribute((const void*)esn_main, hipFuncAttributeMaxDynamicSharedMemorySize, smem_bytes);

  float* outf = (float*)d_out;
  int t0 = 0, t1 = T_;
  void* args[] = {&um, &ua, &wr4, &wi4, &hq, &bar, &S_res, &S_in,
                  &g_res, &g_in, &Woutw, &Woutb, &outf, &t0, &t1};
  hipError_t e = hipLaunchCooperativeKernel((const void*)esn_main, dim3(NWG), dim3(NTHREADS),
                                            args, smem_bytes, stream);
  if (e != hipSuccess) {
    // fallback: one launch per timestep (kernel boundary = sync, no barrier)
    for (int t = 0; t < T_; ++t) {
      hipLaunchKernelGGL(esn_main, dim3(NWG), dim3(NTHREADS), smem_bytes, stream,
                         um, ua, wr4, wi4, hq, bar, S_res, S_in, g_res, g_in,
                         Woutw, Woutb, outf, t, t + 1);
    }
  }
}

// Round 2
// 1985.062 us; speedup vs baseline: 5.4575x; 5.4575x over previous
//
#include <hip/hip_runtime.h>
#include <hip/hip_bf16.h>

// ESN recurrence, B=16 T=512 F=512 H=2048 V=64.
// Integer matvecs exact (int4 packed, v_dot8_i32_i4). FP path replicates
// XLA/Eigen f32 tanh. Per-batch 16-WG slice groups exchange 1KB packed h per
// step via relaxed agent-scope atomics (sc1, no cache-wide maintenance) with
// per-slice flag lines. Readout deferred to a separate GEMM kernel.

#define B_ 16
#define T_ 512
#define F_ 512
#define H_ 2048
#define V_ 64
#define SLICES 16
#define RPW 128      // rows per workgroup (H / SLICES)
#define NTHREADS 256
#define NWG 256      // 16 batches x 16 slices

#if defined(__has_builtin)
#if __has_builtin(__builtin_amdgcn_sdot8)
#define HAVE_SDOT8 1
#endif
#endif

__device__ __forceinline__ int sdot8(int a, int b, int c) {
#ifdef HAVE_SDOT8
  return __builtin_amdgcn_sdot8(a, b, c, false);
#else
#pragma unroll
  for (int i = 0; i < 8; ++i) {
    int av = (a << (28 - 4 * i)) >> 28;
    int bv = (b << (28 - 4 * i)) >> 28;
    c += av * bv;
  }
  return c;
#endif
}

// XLA / Eigen generic_fast_tanh_float, f32, fma form (bit-matching matters:
// quantized recurrence is chaotic at ULP level).
__device__ __forceinline__ float tanh_ref(float x) {
  float ax = fabsf(x);
  float xc = fminf(fmaxf(x, -7.90531110763549805f), 7.90531110763549805f);
  float x2 = __fmul_rn(xc, xc);
  float p = -2.76076847742355e-16f;
  p = __fmaf_rn(x2, p, 2.00018790482477e-13f);
  p = __fmaf_rn(x2, p, -8.60467152213735e-11f);
  p = __fmaf_rn(x2, p, 5.12229709037114e-08f);
  p = __fmaf_rn(x2, p, 1.48572235717979e-05f);
  p = __fmaf_rn(x2, p, 6.37261928875436e-04f);
  p = __fmaf_rn(x2, p, 4.89352455891786e-03f);
  p = __fmul_rn(xc, p);
  float q = 1.19825839466702e-06f;
  q = __fmaf_rn(x2, q, 1.18534705686654e-04f);
  q = __fmaf_rn(x2, q, 2.26843463243900e-03f);
  q = __fmaf_rn(x2, q, 4.89352518554385e-03f);
  float r = __fdiv_rn(p, q);
  return (ax < 0.0004f) ? x : r;
}

__device__ __forceinline__ unsigned f2bf(float f) {  // f32 -> bf16 bits, RNE (no NaN inputs)
  unsigned u = __float_as_uint(f);
  return (u + 0x7fffu + ((u >> 16) & 1u)) >> 16;
}

// ---- prep: pack weights to int4 nibbles ------------------------------------
__global__ void pack_weights(const int* __restrict__ Wres, const int* __restrict__ Win,
                             int* __restrict__ wr4, int* __restrict__ wi4) {
  int id = blockIdx.x * blockDim.x + threadIdx.x;
  if (id < H_ * 256) {
    const int* src = Wres + id * 8;
    int pk = 0;
#pragma unroll
    for (int i = 0; i < 8; ++i) pk |= (src[i] & 15) << (4 * i);
    wr4[id] = pk;
  } else {
    int id2 = id - H_ * 256;
    if (id2 < H_ * 64) {
      const int* src = Win + id2 * 8;
      int pk = 0;
#pragma unroll
      for (int i = 0; i < 8; ++i) pk |= (src[i] & 15) << (4 * i);
      wi4[id2] = pk;
    }
  }
}

// ---- prep: quantize input, split u = 8*a + m into two int4 planes ----------
__global__ void pack_u(const float* __restrict__ x, int* __restrict__ um, int* __restrict__ ua) {
  int idx = blockIdx.x * blockDim.x + threadIdx.x;
  if (idx >= B_ * T_ * 64) return;
  const float* src = x + (size_t)idx * 8;
  int pm = 0, pa = 0;
#pragma unroll
  for (int i = 0; i < 8; ++i) {
    int u = (int)rintf(__fmul_rn(src[i], 3.0f));  // round-half-even == jnp.round
    int vv = u + 128;
    pm |= (vv & 7) << (4 * i);
    pa |= (((vv >> 3) - 16) & 15) << (4 * i);
  }
  um[idx] = pm;
  ua[idx] = pa;
}

// ---- main persistent kernel ------------------------------------------------
// WG = (batch b = wg&15, slice = wg>>4). W_res slice rows live in REGISTERS
// (32 int4/thread). h exchange: 16 dwords/slice via relaxed agent atomics,
// per-slice flag line, double-buffered. No fences, no LDS weight traffic.
__global__ void __launch_bounds__(NTHREADS, 1) esn_main(
    const int* __restrict__ um, const int* __restrict__ ua,
    const int* __restrict__ wr4, const int* __restrict__ wi4,
    int* __restrict__ hq, int* __restrict__ flg,
    const float* __restrict__ S_res, const float* __restrict__ S_in,
    const float* __restrict__ g_res, const float* __restrict__ g_in,
    unsigned* __restrict__ Hs, int t0, int t1) {
  __shared__ int lds_h4[256];
  __shared__ int lds_um[64];
  __shared__ int lds_ua[64];
  __shared__ float lds_hf[128];
  __shared__ signed char lds_h8[128];

  const int wg = blockIdx.x;
  const int b = wg & 15, slice = wg >> 4;
  const int tid = threadIdx.x;
  const int r = tid >> 1, half = tid & 1;
  const int grow = slice * RPW + r;

  // W_res slice rows -> registers (128 VGPRs), W_in -> registers (32 VGPRs)
  ::int4 wreg[32];
  {
    const ::int4* gw = (const ::int4*)wr4;  // 64 int4 per row
#pragma unroll
    for (int m = 0; m < 32; ++m) wreg[m] = gw[grow * 64 + half * 32 + m];
  }
  ::int4 rwm[8];
  {
    const ::int4* gwi = (const ::int4*)wi4;  // 16 int4 per row
#pragma unroll
    for (int m = 0; m < 8; ++m) rwm[m] = gwi[grow * 16 + half * 8 + m];
  }
  float sr = 0.f, si = 0.f;
  if (half == 0) {
    sr = __fmul_rn(__fdiv_rn(S_res[grow], 49.0f), g_res[0]);
    si = __fmul_rn(__fdiv_rn(S_in[grow], 21.0f), g_in[0]);
  }

  const ::int4* lh4 = (const ::int4*)lds_h4 + half * 32;
  const ::int4* lum4 = (const ::int4*)lds_um + half * 8;
  const ::int4* lua4 = (const ::int4*)lds_ua + half * 8;

  for (int t = t0; t < t1; ++t) {
    const int cur = t & 1, nxt = cur ^ 1;
    // stage u nibbles (static data, no ordering needed)
    if (tid < 64)
      lds_um[tid] = um[(b * T_ + t) * 64 + tid];
    else if (tid < 128)
      lds_ua[tid - 64] = ua[(b * T_ + t) * 64 + (tid - 64)];
    // wait for all 16 producers of h_t (parallel poll, one flag line each)
    if (tid < 16) {
      while (__hip_atomic_load(&flg[(b * 16 + tid) * 16], __ATOMIC_RELAXED,
                               __HIP_MEMORY_SCOPE_AGENT) < t)
        __builtin_amdgcn_s_sleep(1);
    }
    __syncthreads();
    // stage packed h (coherent loads, bypass stale L2 copies)
    lds_h4[tid] = __hip_atomic_load(&hq[(cur * 16 + b) * 256 + tid], __ATOMIC_RELAXED,
                                    __HIP_MEMORY_SCOPE_AGENT);
    __syncthreads();

    // recurrent dot from registers
    int acc = 0;
#pragma unroll
    for (int m = 0; m < 32; ++m) {
      ::int4 w = wreg[m];
      ::int4 h = lh4[m];
      acc = sdot8(w.x, h.x, acc);
      acc = sdot8(w.y, h.y, acc);
      acc = sdot8(w.z, h.z, acc);
      acc = sdot8(w.w, h.w, acc);
    }
    // input dot: u = 8a + m split
    int am = 0, aa = 0;
#pragma unroll
    for (int m = 0; m < 8; ++m) {
      ::int4 w = rwm[m];
      ::int4 uM = lum4[m];
      ::int4 uA = lua4[m];
      am = sdot8(w.x, uM.x, am); am = sdot8(w.y, uM.y, am);
      am = sdot8(w.z, uM.z, am); am = sdot8(w.w, uM.w, am);
      aa = sdot8(w.x, uA.x, aa); aa = sdot8(w.y, uA.y, aa);
      aa = sdot8(w.z, uA.z, aa); aa = sdot8(w.w, uA.w, aa);
    }
    int accin = am + (aa << 3);
    acc += __shfl_xor(acc, 1);
    accin += __shfl_xor(accin, 1);

    if (half == 0) {
      int cr = min(max(acc, -32768), 32767);
      int ci = min(max(accin, -32768), 32767);
      float arg = __fadd_rn(__fmul_rn((float)cr, sr), __fmul_rn((float)ci, si));
      float hn = tanh_ref(arg);
      float hc = fminf(fmaxf(hn, -1.0f), 1.0f);
      int qv = (int)rintf(__fmul_rn(hc, 7.0f));
      lds_h8[r] = (signed char)qv;
      lds_hf[r] = hn;
    }
    __syncthreads();

    // store h_t (bf16 pair pack) for deferred readout — plain stores
    if (tid < 64) {
      float h0 = lds_hf[2 * tid], h1 = lds_hf[2 * tid + 1];
      Hs[((size_t)(b * T_ + t) * H_ + slice * RPW) / 2 + tid] = f2bf(h0) | (f2bf(h1) << 16);
    }
    // publish packed next-h (wave 0 only), then flag after vmcnt drain
    if (tid < 16) {
      int pk = 0;
#pragma unroll
      for (int i = 0; i < 8; ++i) pk |= (lds_h8[tid * 8 + i] & 15) << (4 * i);
      __hip_atomic_store(&hq[(nxt * 16 + b) * 256 + slice * 16 + tid], pk, __ATOMIC_RELAXED,
                         __HIP_MEMORY_SCOPE_AGENT);
    }
    asm volatile("s_waitcnt vmcnt(0)" ::: "memory");  // data stores reach coherence point
    if (tid == 0)
      __hip_atomic_store(&flg[(b * 16 + slice) * 16], t + 1, __ATOMIC_RELAXED,
                         __HIP_MEMORY_SCOPE_AGENT);
  }
}

// ---- deferred readout: out[bt,v] = bias[v] + sum_h Hs[bt,h]*Wout[v,h] ------
// block = 256 thr = 16 bt-rows x 16 v-cols; grid = (BT/16, V/16)
__global__ void __launch_bounds__(256) readout(const unsigned* __restrict__ Hs,
                                               const float* __restrict__ Wout,
                                               const float* __restrict__ Wb,
                                               float* __restrict__ out) {
  const int v = (blockIdx.y << 4) + (threadIdx.x & 15);
  const int bt = (blockIdx.x << 4) + (threadIdx.x >> 4);
  const unsigned* hrow = Hs + (size_t)bt * (H_ / 2);
  const float* wrow = Wout + (size_t)v * H_;
  float acc = Wb[v];
  for (int j = 0; j < H_ / 2; j += 4) {
    uint4 hp = *(const uint4*)(hrow + j);
    float4 w0 = *(const float4*)(wrow + 2 * j);
    float4 w1 = *(const float4*)(wrow + 2 * j + 4);
    acc = fmaf(__uint_as_float(hp.x << 16), w0.x, acc);
    acc = fmaf(__uint_as_float(hp.x & 0xffff0000u), w0.y, acc);
    acc = fmaf(__uint_as_float(hp.y << 16), w0.z, acc);
    acc = fmaf(__uint_as_float(hp.y & 0xffff0000u), w0.w, acc);
    acc = fmaf(__uint_as_float(hp.z << 16), w1.x, acc);
    acc = fmaf(__uint_as_float(hp.z & 0xffff0000u), w1.y, acc);
    acc = fmaf(__uint_as_float(hp.w << 16), w1.z, acc);
    acc = fmaf(__uint_as_float(hp.w & 0xffff0000u), w1.w, acc);
  }
  out[(size_t)bt * V_ + v] = acc;
}

extern "C" void kernel_launch(void* const* d_in, const int* in_sizes, int n_in,
                              void* d_out, int out_size, void* d_ws, size_t ws_size,
                              hipStream_t stream) {
  const float* x = (const float*)d_in[0];
  const float* S_res = (const float*)d_in[1];
  const float* S_in = (const float*)d_in[2];
  const float* g_res = (const float*)d_in[3];
  const float* g_in = (const float*)d_in[4];
  const float* Woutw = (const float*)d_in[5];
  const float* Woutb = (const float*)d_in[6];
  const int* Wres = (const int*)d_in[7];
  const int* Win = (const int*)d_in[8];

  char* ws = (char*)d_ws;
  int* flg = (int*)(ws);                 // 256 flags x 64B stride = 16 KiB
  int* hq = (int*)(ws + 16384);          // 2 x 16 x 256 dw = 32 KiB
  int* um = (int*)(ws + 65536);          // 2 MiB
  int* ua = um + 524288;                 // 2 MiB
  int* wr4 = ua + 524288;                // 2 MiB
  int* wi4 = wr4 + 524288;               // 512 KiB
  unsigned* Hs = (unsigned*)(ws + 8 * 1024 * 1024);  // 32 MiB bf16 h history

  hipMemsetAsync(d_ws, 0, 49152, stream);  // flags + hq (h0 = 0)
  hipLaunchKernelGGL(pack_weights, dim3(2560), dim3(256), 0, stream, Wres, Win, wr4, wi4);
  hipLaunchKernelGGL(pack_u, dim3(2048), dim3(256), 0, stream, x, um, ua);

  float* outf = (float*)d_out;
  int t0 = 0, t1 = T_;
  void* args[] = {&um, &ua, &wr4, &wi4, &hq, &flg, &S_res, &S_in,
                  &g_res, &g_in, &Hs, &t0, &t1};
  hipError_t e = hipLaunchCooperativeKernel((const void*)esn_main, dim3(NWG), dim3(NTHREADS),
                                            args, 0, stream);
  if (e != hipSuccess) {
    // fallback: one launch per timestep (kernel boundary = sync)
    for (int t = 0; t < T_; ++t) {
      hipLaunchKernelGGL(esn_main, dim3(NWG), dim3(NTHREADS), 0, stream,
                         um, ua, wr4, wi4, hq, flg, S_res, S_in, g_res, g_in, Hs, t, t + 1);
    }
  }
  hipLaunchKernelGGL(readout, dim3(B_ * T_ / 16, V_ / 16), dim3(256), 0, stream,
                     Hs, Woutw, Woutb, outf);
}